// Round 3
// baseline (555.203 us; speedup 1.0000x reference)
//
#include <hip/hip_runtime.h>
#include <stdint.h>

#define HIDDEN 512
#define ONEHOT 64
#define EDIM   576   // HIDDEN + ONEHOT
#define BATCH  128
#define LSEQ   1024
#define FANIN  1088  // 2*HIDDEN + ONEHOT

typedef __attribute__((ext_vector_type(8))) short short8;
typedef __attribute__((ext_vector_type(4))) float f32x4;

__device__ inline unsigned short f2bf(float x) {
    union { float f; unsigned int u; } v; v.f = x;
    unsigned int u = v.u;
    unsigned int r = (u + 0x7FFFu + ((u >> 16) & 1u)) >> 16;  // RNE
    return (unsigned short)r;
}

__device__ inline float fast_tanh(float x) {
    float ax = fabsf(x);
    float e  = __expf(2.f * ax);
    float t  = 1.f - __fdividef(2.f, e + 1.f);
    return copysignf(t, x);
}

// ---- prep: part_h[b][h] = hidden.W[:, :512]^T + bias  AND  We -> bf16 -----
// WeB layout: [kc 9][h 512][g' 8][j 8], where the element stored at group g'
// is logical k = (g' ^ (h&7))*8 + j  -- an XOR swizzle so the LDS image
// (loaded via global_load_lds, lane*16B order) has conflict-free frag reads.
__global__ __launch_bounds__(256) void k_prep(const float* __restrict__ hidden,
                                              const float* __restrict__ W,
                                              const float* __restrict__ bias,
                                              float* __restrict__ ph,
                                              unsigned short* __restrict__ WeB) {
    int bid = blockIdx.x;
    int tid = threadIdx.x;
    if (bid < 256) {
        int gid = bid * 256 + tid;                 // 65536 threads
        int b = gid & (BATCH - 1);
        int h = gid >> 7;
        const float* hrow = hidden + b * HIDDEN;
        const float* wrow = W + h * FANIN;
        float acc = 0.f;
#pragma unroll 8
        for (int d = 0; d < HIDDEN; d += 4) {
            float4 hv = *(const float4*)(hrow + d);
            float4 wv = *(const float4*)(wrow + d);
            acc += hv.x * wv.x + hv.y * wv.y + hv.z * wv.z + hv.w * wv.w;
        }
        ph[b * HIDDEN + h] = acc + bias[h];
    } else {
        int i = (bid - 256) * 256 + tid;           // 0..294911
        int kc = i >> 15;                          // 0..8
        int h  = (i >> 6) & 511;
        int g  = (i >> 3) & 7;                     // physical 16B group
        int j  = i & 7;
        int k  = ((g ^ (h & 7)) << 3) | j;         // logical k in chunk
        WeB[i] = f2bf(W[h * FANIN + HIDDEN + kc * 64 + k]);
    }
}

// ---- main fused GEMM + tanh + v-dot ---------------------------------------
// 8-phase-style schedule (T3+T4+T5, m201 geometry adapted):
//   block tile 256m x 256n, BK=64, 512 thr = 8 waves (2m x 4n),
//   wave tile 128x64, acc[8][4] f32x4 (128 VGPR).
// Per K-step: 4 phase-pairs {frag ds_reads; barrier; setprio1; 16 MFMA;
// setprio0; barrier}. Staging T14-split: A fp32 globals + B global_load_lds
// issued at P0 into [nxt]; vmcnt(4) + cvt + ds_write at P3; ONE
// __syncthreads per K-step (its vmcnt(0) lands 3 phases after issue).
// A dbuf + B dbuf in 139 KB dynamic LDS (1 block/CU, HK-style).
#define AROW 72   // ushorts per A-LDS row = 144 B (16B-aligned)
#define ABUF (256 * AROW)          // ushorts per A buffer (18432)
#define ABYTES (2 * ABUF * 2)      // 73728
#define BBUF 32768                 // bytes per B buffer
#define LDS_TOTAL (ABYTES + 2 * BBUF)   // 139264

__global__ __launch_bounds__(512, 2) void k_main(
        const float* __restrict__ enc,            // [L][B][EDIM] fp32
        const unsigned short* __restrict__ WeB,   // swizzled [9][512][64] bf16
        const float* __restrict__ ph,             // [B][HIDDEN] (bias included)
        const float* __restrict__ v,
        float* __restrict__ scoresP)              // [8 slots][B][L] partials
{
    extern __shared__ __align__(16) char smem[];
    unsigned short* aLds = (unsigned short*)smem;    // [2][256*AROW] ushorts
    char* bLdsB = smem + ABYTES;                     // [2][32768] bytes

    const int tid  = threadIdx.x;
    const int wave = tid >> 6;
    const int lane = tid & 63;
    const int c  = lane & 15;
    const int q  = lane >> 4;
    const int wr = wave >> 2;     // 0..1  m half (128 rows)
    const int wc = wave & 3;      // 0..3  n quarter (64 cols)

    // XCD-bijective decode: id = xcd + 8*s; nt = s&1; mt = (s>>1) + 64*xcd.
    // The two nt-blocks of one mt share the A-tile and land on the same XCD.
    const int id  = blockIdx.x;
    const int xcd = id & 7;
    const int sq_ = id >> 3;
    const int nt  = sq_ & 1;
    const int mt  = (sq_ >> 1) + 64 * xcd;    // 0..511
    const int l0  = mt * 2;
    const int hbase = nt * 256;

    f32x4 acc[8][4];
#pragma unroll
    for (int i = 0; i < 8; ++i)
#pragma unroll
        for (int j = 0; j < 4; ++j) acc[i][j] = (f32x4){0.f, 0.f, 0.f, 0.f};

    // A tile: rows r in [0,256) = 2 consecutive l's (enc is l-major, so the
    // 256 rows are contiguous with stride EDIM).
    const float* abase = enc + (size_t)l0 * (BATCH * EDIM);
    const char*  bsrc  = (const char*)WeB + nt * 32768;   // per-kc stride 65536

    const int r0 = tid >> 4;              // 0..31
    const int c4 = tid & 15;
    const float* aptr = abase + (size_t)r0 * EDIM + c4 * 4;
    unsigned short* awbase = aLds + r0 * AROW + c4 * 4;

    float4 av[8];

#define STAGE_ISSUE(KOFF, NXT) do {                                           \
    const float* asrc_ = aptr + (KOFF) * 64;                                  \
    _Pragma("unroll")                                                         \
    for (int fi = 0; fi < 8; ++fi)                                            \
        av[fi] = *(const float4*)(asrc_ + (size_t)fi * 32 * EDIM);            \
    const char* bs_ = bsrc + (size_t)(KOFF) * 65536;                          \
    char* bd_ = bLdsB + (NXT) * BBUF;                                         \
    _Pragma("unroll")                                                         \
    for (int rr = 0; rr < 4; ++rr) {                                          \
        int off_ = rr * 8192 + wave * 1024 + lane * 16;                       \
        __builtin_amdgcn_global_load_lds(                                     \
            (const __attribute__((address_space(1))) unsigned int*)(bs_ + off_), \
            (__attribute__((address_space(3))) unsigned int*)(bd_ + off_),    \
            16, 0, 0);                                                        \
    }                                                                         \
} while (0)

#define CVT_WRITE(NXT) do {                                                   \
    unsigned short* ad_ = awbase + (NXT) * ABUF;                              \
    _Pragma("unroll")                                                         \
    for (int fi = 0; fi < 8; ++fi) {                                          \
        ushort4 w_;                                                           \
        w_.x = f2bf(av[fi].x); w_.y = f2bf(av[fi].y);                         \
        w_.z = f2bf(av[fi].z); w_.w = f2bf(av[fi].w);                         \
        *(ushort4*)(ad_ + fi * 32 * AROW) = w_;                               \
    }                                                                         \
} while (0)

#define LOAD_AFRAGS(MQ, KK)                                                   \
    _Pragma("unroll")                                                         \
    for (int i = 0; i < 4; ++i)                                               \
        af[i] = *(const short8*)(aC + (size_t)(wr * 128 + ((MQ)*4 + i) * 16 + c) * AROW + (KK) * 32 + q * 8);

#define LOAD_BFRAGS(KK) do {                                                  \
    const int g_ = (((KK) << 2) | q) ^ (c & 7);                               \
    _Pragma("unroll")                                                         \
    for (int j = 0; j < 4; ++j)                                               \
        bf[j] = *(const short8*)(bC + (wc * 64 + j * 16 + c) * 128 + g_ * 16); \
} while (0)

#define PHASE_COMPUTE(MQ) do {                                                \
    __builtin_amdgcn_s_setprio(1);                                            \
    _Pragma("unroll")                                                         \
    for (int i = 0; i < 4; ++i)                                               \
        _Pragma("unroll")                                                     \
        for (int j = 0; j < 4; ++j)                                           \
            acc[(MQ)*4 + i][j] = __builtin_amdgcn_mfma_f32_16x16x32_bf16(     \
                af[i], bf[j], acc[(MQ)*4 + i][j], 0, 0, 0);                   \
    __builtin_amdgcn_s_setprio(0);                                            \
} while (0)

    // ---- prologue: stage kc=0 into buffers 0 ----
    STAGE_ISSUE(0, 0);
    asm volatile("s_waitcnt vmcnt(4)" ::: "memory");   // A(0) regs ready
    CVT_WRITE(0);
    __syncthreads();   // drains DMA(0) (vmcnt 0) + A writes (lgkm 0)

    for (int kc = 0; kc < 9; ++kc) {
        const int cur = kc & 1;
        const int nxt = cur ^ 1;
        const unsigned short* aC = aLds + cur * ABUF;
        const char* bC = bLdsB + cur * BBUF;
        short8 af[4], bf[4];

        // ---- P0: kk=0, m-quad 0; issue next-step staging ----
        LOAD_BFRAGS(0);
        LOAD_AFRAGS(0, 0);
        if (kc < 8) STAGE_ISSUE(kc + 1, nxt);
        __builtin_amdgcn_s_barrier();
        PHASE_COMPUTE(0);
        __builtin_amdgcn_s_barrier();

        // ---- P1: kk=0, m-quad 1 ----
        LOAD_AFRAGS(1, 0);
        __builtin_amdgcn_s_barrier();
        PHASE_COMPUTE(1);
        __builtin_amdgcn_s_barrier();

        // ---- P2: kk=1, m-quad 0 ----
        LOAD_BFRAGS(1);
        LOAD_AFRAGS(0, 1);
        __builtin_amdgcn_s_barrier();
        PHASE_COMPUTE(0);
        __builtin_amdgcn_s_barrier();

        // ---- P3: kk=1, m-quad 1; publish next-step buffers ----
        LOAD_AFRAGS(1, 1);
        if (kc < 8) {
            asm volatile("s_waitcnt vmcnt(4)" ::: "memory"); // A regs ready,
            CVT_WRITE(nxt);                                  // 4 DMA in flight
            __syncthreads();   // vmcnt(0): DMA(kc+1) done (issued 3 phases
                               // ago); lgkm(0): A writes done. Publish.
        }
        PHASE_COMPUTE(1);
    }

    // ---- epilogue: tanh, v-dot, reduce over 16 c-lanes, slot store --------
    float vv[4];
#pragma unroll
    for (int j = 0; j < 4; ++j) vv[j] = v[hbase + wc * 64 + j * 16 + c];

    const int slot = nt * 4 + wc;
#pragma unroll
    for (int mb = 0; mb < 8; ++mb) {
#pragma unroll
        for (int rr = 0; rr < 4; ++rr) {
            int row = wr * 128 + mb * 16 + q * 4 + rr;   // 0..255
            int b   = row & 127;
            int ll  = l0 + (row >> 7);
            const float* phr = ph + b * HIDDEN + hbase + wc * 64 + c;
            float s = 0.f;
#pragma unroll
            for (int j = 0; j < 4; ++j) {
                float e = acc[mb][j][rr] + phr[j * 16];
                s += vv[j] * fast_tanh(e);
            }
            s += __shfl_xor(s, 1);
            s += __shfl_xor(s, 2);
            s += __shfl_xor(s, 4);
            s += __shfl_xor(s, 8);
            if (c == 0)
                scoresP[((size_t)slot * BATCH + b) * LSEQ + ll] = s;
        }
    }
#undef STAGE_ISSUE
#undef CVT_WRITE
#undef LOAD_AFRAGS
#undef LOAD_BFRAGS
#undef PHASE_COMPUTE
}

// ---- softmax over L per batch row; sums the 8 partial slots ---------------
__global__ __launch_bounds__(256) void k_softmax(const float* __restrict__ sp,
                                                 float* __restrict__ out) {
    __shared__ float red[4];
    int b = blockIdx.x;
    int tid = threadIdx.x;
    float vals[4];
#pragma unroll
    for (int i = 0; i < 4; ++i) {
        int li = tid + i * 256;
        float s = 0.f;
#pragma unroll
        for (int sl = 0; sl < 8; ++sl)
            s += sp[((size_t)sl * BATCH + b) * LSEQ + li];   // coalesced
        vals[i] = s;
    }

    float m = fmaxf(fmaxf(vals[0], vals[1]), fmaxf(vals[2], vals[3]));
    for (int off = 1; off < 64; off <<= 1) m = fmaxf(m, __shfl_xor(m, off));
    int wv = tid >> 6;
    if ((tid & 63) == 0) red[wv] = m;
    __syncthreads();
    m = fmaxf(fmaxf(red[0], red[1]), fmaxf(red[2], red[3]));
    __syncthreads();

    float sum = 0.f;
#pragma unroll
    for (int i = 0; i < 4; ++i) { vals[i] = __expf(vals[i] - m); sum += vals[i]; }
    for (int off = 1; off < 64; off <<= 1) sum += __shfl_xor(sum, off);
    if ((tid & 63) == 0) red[wv] = sum;
    __syncthreads();
    sum = red[0] + red[1] + red[2] + red[3];
    float inv = 1.f / sum;
#pragma unroll
    for (int i = 0; i < 4; ++i)
        out[(size_t)b * LSEQ + tid + i * 256] = vals[i] * inv;
}

extern "C" void kernel_launch(void* const* d_in, const int* in_sizes, int n_in,
                              void* d_out, int out_size, void* d_ws, size_t ws_size,
                              hipStream_t stream) {
    const float* hidden = (const float*)d_in[0];   // [128][512]
    const float* enc    = (const float*)d_in[1];   // [1024][128][576]
    const float* W      = (const float*)d_in[2];   // [512][1088]
    const float* bias   = (const float*)d_in[3];   // [512]
    const float* v      = (const float*)d_in[4];   // [512]
    float* out = (float*)d_out;                    // [128][1][1024]
    (void)ws_size;

    char* ws = (char*)d_ws;
    float* ph           = (float*)ws;                       // 256 KB
    unsigned short* WeB = (unsigned short*)(ws + 262144);   // 576 KB
    float* scoresP      = (float*)(ws + 851968);            // 4 MB [8][B][L]

    hipFuncSetAttribute((const void*)k_main,
                        hipFuncAttributeMaxDynamicSharedMemorySize, LDS_TOTAL);

    hipLaunchKernelGGL(k_prep, dim3(1408), dim3(256), 0, stream,
                       hidden, W, bias, ph, WeB);
    hipLaunchKernelGGL(k_main, dim3(1024), dim3(512), LDS_TOTAL, stream,
                       enc, WeB, ph, v, scoresP);
    hipLaunchKernelGGL(k_softmax, dim3(128), dim3(256), 0, stream, scoresP, out);
}